// Round 5
// baseline (1034.777 us; speedup 1.0000x reference)
//
#include <hip/hip_runtime.h>
#include <stdint.h>

#define IN_DIM 1280
#define HID    5120
#define NROWS  8192        // 32*16*16
#define HW     256
#define XB_STRIDE (IN_DIM*HW)             // 327680
#define FEATS_ELEMS (2ull*NROWS*HID)      // 83886080 floats
#define RECON_ELEMS ((size_t)NROWS*IN_DIM) // 10485760 floats

#define CAND_CAP 80
// margin > 2*(gemm bf16 err + bf16 storage half-ulp @ v~1.5) = 2*(0.0075+0.0039)
#define CAND_MARGIN 0.024f

typedef __attribute__((ext_vector_type(8))) short bf16x8;
typedef __attribute__((ext_vector_type(4))) float f32x4;
typedef unsigned short ushort_t;

__device__ inline ushort_t f32_to_bf16(float f) {
    uint32_t u = __float_as_uint(f);
    u += 0x7fff + ((u >> 16) & 1);            // round-to-nearest-even
    return (ushort_t)(u >> 16);
}

__device__ inline float bf16_to_f32(ushort_t h) {
    return __uint_as_float((uint32_t)h << 16);
}

__device__ inline void load_lds16(const void* g, void* l) {
    __builtin_amdgcn_global_load_lds(
        (const __attribute__((address_space(1))) uint32_t*)g,
        (__attribute__((address_space(3))) uint32_t*)l, 16, 0, 0);
}

// ---- K1 (merged): all input conversions in one dispatch ----
#define NBLK_A 10240
#define NBLK_B 6400
#define NBLK_C 6400

__global__ __launch_bounds__(256) void convert_all(const float* __restrict__ x,
        const float* __restrict__ W_enc, const float* __restrict__ W_dec,
        ushort_t* __restrict__ Abf, float* __restrict__ xT,
        ushort_t* __restrict__ Wbf, float* __restrict__ Wf,
        ushort_t* __restrict__ Wdec_bf) {
    __shared__ float s[32][33];
    const int bid = blockIdx.x;
    const int tx = threadIdx.x & 31, ty0 = threadIdx.x >> 5;
    if (bid < NBLK_A) {
        const int c0 = (bid % 40) * 32, hw0 = ((bid / 40) & 7) * 32, b = bid / 320;
        const float* src = x + (size_t)b * XB_STRIDE;
        #pragma unroll
        for (int r = 0; r < 4; r++) {
            int c = c0 + ty0*4 + r;
            s[ty0*4+r][tx] = src[(size_t)c * HW + hw0 + tx];
        }
        __syncthreads();
        #pragma unroll
        for (int r = 0; r < 4; r++) {
            int hw = hw0 + ty0*4 + r;
            int n = b*256 + hw;
            float v = s[tx][ty0*4+r];
            Abf[(size_t)n * IN_DIM + c0 + tx] = f32_to_bf16(v);
            xT [(size_t)n * IN_DIM + c0 + tx] = v;
        }
    } else if (bid < NBLK_A + NBLK_B) {
        const int b2 = bid - NBLK_A;
        const int j0 = (b2 % 160) * 32, c0 = (b2 / 160) * 32;
        #pragma unroll
        for (int r = 0; r < 4; r++) {
            int c = c0 + ty0*4 + r;
            s[ty0*4+r][tx] = W_enc[(size_t)c * HID + j0 + tx];
        }
        __syncthreads();
        #pragma unroll
        for (int r = 0; r < 4; r++) {
            int j = j0 + ty0*4 + r;
            float v = s[tx][ty0*4+r];
            Wbf[(size_t)j * IN_DIM + c0 + tx] = f32_to_bf16(v);
            Wf [(size_t)j * IN_DIM + c0 + tx] = v;
        }
    } else {
        const int b3 = bid - NBLK_A - NBLK_B;
        size_t i = ((size_t)b3 * 256 + threadIdx.x) * 4;
        float4 v = *(const float4*)&W_dec[i];
        Wdec_bf[i+0] = f32_to_bf16(v.x);
        Wdec_bf[i+1] = f32_to_bf16(v.y);
        Wdec_bf[i+2] = f32_to_bf16(v.z);
        Wdec_bf[i+3] = f32_to_bf16(v.w);
    }
}

// ---- K2: bf16 MFMA GEMM, approx enc = relu(A@W + b) -> bf16 store ----
// (round-3 proven version: 128x128 tile, 2560 blocks, ~3 blocks/CU overlap)
#define BM 128
#define BN 128
#define BK 32

__global__ __launch_bounds__(256) void encode_mfma(const ushort_t* __restrict__ A,
        const ushort_t* __restrict__ B, const float* __restrict__ b_enc,
        ushort_t* __restrict__ C) {
    __shared__ __align__(16) ushort_t As[BM*BK];   // [128 rows][32 k] = 8 KB
    __shared__ __align__(16) ushort_t Bs[BN*BK];
    const int n0 = blockIdx.x * BN;
    const int m0 = blockIdx.y * BM;
    const int t = threadIdx.x;
    const int lane = t & 63, w = t >> 6;
    const int mr0 = (w >> 1) * 64, nc0 = (w & 1) * 64;
    const int lm = lane & 15, lq = lane >> 4;
    const int srow_l = w*16 + (lane >> 2);
    const int skof   = (lane & 3) * 8;

    f32x4 acc[4][4];
    #pragma unroll
    for (int i = 0; i < 4; i++)
        #pragma unroll
        for (int j = 0; j < 4; j++)
            #pragma unroll
            for (int q = 0; q < 4; q++) acc[i][j][q] = 0.f;

    for (int k0 = 0; k0 < IN_DIM; k0 += BK) {
        #pragma unroll
        for (int h = 0; h < 2; h++) {
            const ushort_t* ga = &A[(size_t)(m0 + h*64 + srow_l)*IN_DIM + k0 + skof];
            const ushort_t* gb = &B[(size_t)(n0 + h*64 + srow_l)*IN_DIM + k0 + skof];
            load_lds16(ga, &As[(h*64 + w*16)*BK]);
            load_lds16(gb, &Bs[(h*64 + w*16)*BK]);
        }
        __syncthreads();
        bf16x8 af[4], bfr[4];
        #pragma unroll
        for (int mt = 0; mt < 4; mt++)
            af[mt] = *(const bf16x8*)&As[(mr0 + mt*16 + lm)*BK + lq*8];
        #pragma unroll
        for (int nt = 0; nt < 4; nt++)
            bfr[nt] = *(const bf16x8*)&Bs[(nc0 + nt*16 + lm)*BK + lq*8];
        #pragma unroll
        for (int mt = 0; mt < 4; mt++)
            #pragma unroll
            for (int nt = 0; nt < 4; nt++)
                acc[mt][nt] = __builtin_amdgcn_mfma_f32_16x16x32_bf16(af[mt], bfr[nt], acc[mt][nt], 0, 0, 0);
        __syncthreads();
    }
    #pragma unroll
    for (int mt = 0; mt < 4; mt++) {
        #pragma unroll
        for (int nt = 0; nt < 4; nt++) {
            int col = n0 + nc0 + nt*16 + lm;
            float bias = b_enc[col];
            #pragma unroll
            for (int r = 0; r < 4; r++) {
                int row = m0 + mr0 + mt*16 + lq*4 + r;
                float v = acc[mt][nt][r] + bias;
                C[(size_t)row*HID + col] = f32_to_bf16(v > 0.f ? v : 0.f);
            }
        }
    }
}

// ---- K3: per-row approx-rank-32 threshold (ballot binary search) on bf16 enc ----
__global__ __launch_bounds__(256) void topk_approx(const ushort_t* __restrict__ E,
        int* __restrict__ cand_idx, int* __restrict__ cand_cnt) {
    const int n = blockIdx.x, t = threadIdx.x;
    const ushort_t* row = E + (size_t)n * HID;
    float v[20];
    {
        bf16x8 u0 = *(const bf16x8*)&row[t*16];
        bf16x8 u1 = *(const bf16x8*)&row[t*16 + 8];
        #pragma unroll
        for (int r = 0; r < 8; r++) {
            v[r]   = bf16_to_f32((ushort_t)u0[r]);
            v[r+8] = bf16_to_f32((ushort_t)u1[r]);
        }
        ushort_t u2[4];
        *(uint2*)u2 = *(const uint2*)&row[4096 + t*4];
        #pragma unroll
        for (int r = 0; r < 4; r++) v[16+r] = bf16_to_f32(u2[r]);
    }
    float mx = 0.f;
    #pragma unroll
    for (int r = 0; r < 20; r++) mx = fmaxf(mx, v[r]);
    #pragma unroll
    for (int off = 32; off > 0; off >>= 1) mx = fmaxf(mx, __shfl_down(mx, off));
    __shared__ float smx[4];
    __shared__ int scnt[2][4];
    __shared__ int ccount;
    if ((t & 63) == 0) smx[t >> 6] = mx;
    if (t == 0) ccount = 0;
    __syncthreads();
    float lo = 0.f;
    float hi = fmaxf(fmaxf(smx[0], smx[1]), fmaxf(smx[2], smx[3])) + 1e-6f;
    for (int it = 0; it < 11; it++) {
        float mid = 0.5f * (lo + hi);
        int c = 0;
        #pragma unroll
        for (int r = 0; r < 20; r++)
            c += (int)__popcll(__ballot(v[r] > mid));
        if ((t & 63) == 0) scnt[it & 1][t >> 6] = c;
        __syncthreads();
        int tot = scnt[it & 1][0] + scnt[it & 1][1] + scnt[it & 1][2] + scnt[it & 1][3];
        if (tot >= 32) lo = mid; else hi = mid;
    }
    float thr = lo - CAND_MARGIN;
    #pragma unroll
    for (int r = 0; r < 20; r++) {
        if (v[r] > thr) {
            int p = atomicAdd(&ccount, 1);
            int idx = (r < 16) ? (16*t + r) : (4096 + 4*t + (r - 16));
            if (p < CAND_CAP) cand_idx[(size_t)n * CAND_CAP + p] = idx;
        }
    }
    __syncthreads();
    if (t == 0) cand_cnt[n] = ccount < CAND_CAP ? ccount : CAND_CAP;
}

// ---- K4: fp32 exact-enough recompute of candidates + ordered exact top-32 ----
__global__ __launch_bounds__(256) void refine_topk(const float* __restrict__ xT,
        const float* __restrict__ Wf, const float* __restrict__ b_enc,
        const int* __restrict__ cand_idx, const int* __restrict__ cand_cnt,
        float* __restrict__ out_vals, int* __restrict__ out_idx) {
    const int n = blockIdx.x, t = threadIdx.x;
    const int lane = t & 63, w = t >> 6;
    const int sub = lane >> 4, sl = lane & 15;
    __shared__ __align__(16) float xs[IN_DIM];
    __shared__ int cidx[128];
    __shared__ float cval[128];
    __shared__ float svals[32];
    __shared__ int sidxs[32];
    const int cnt = cand_cnt[n];
    #pragma unroll
    for (int i = 0; i < 5; i++) xs[t + 256*i] = xT[(size_t)n*IN_DIM + t + 256*i];
    if (t < 128) {
        cidx[t] = (t < cnt) ? cand_idx[(size_t)n*CAND_CAP + t] : 0x7fffffff;
        cval[t] = -1.f;
    }
    __syncthreads();
    const int slot = w*4 + sub;          // 0..15
    const int iters = (cnt + 15) >> 4;
    for (int it = 0; it < iters; it++) {
        int i = it*16 + slot;
        if (i < cnt) {
            int j = cidx[i];
            const float4* wr2 = (const float4*)(Wf + (size_t)j * IN_DIM);
            const float4* xr = (const float4*)xs;
            float a0 = 0.f, a1 = 0.f, a2 = 0.f, a3 = 0.f;
            #pragma unroll
            for (int r = 0; r < 20; r++) {
                float4 wv = wr2[sl + 16*r];
                float4 xv = xr[sl + 16*r];
                a0 = fmaf(xv.x, wv.x, a0);
                a1 = fmaf(xv.y, wv.y, a1);
                a2 = fmaf(xv.z, wv.z, a2);
                a3 = fmaf(xv.w, wv.w, a3);
            }
            float s = (a0 + a1) + (a2 + a3);
            #pragma unroll
            for (int off = 8; off > 0; off >>= 1)
                s += __shfl_down(s, off);
            if (sl == 0) {
                float fv = s + b_enc[j];
                cval[i] = fv > 0.f ? fv : 0.f;
            }
        }
    }
    __syncthreads();
    if (w == 0) {
        float v0 = cval[lane], v1 = cval[lane + 64];
        int j0 = cidx[lane], j1 = cidx[lane + 64];
        for (int it = 0; it < 32; it++) {
            bool take1 = (v1 > v0) || (v1 == v0 && j1 < j0);
            float bv = take1 ? v1 : v0;
            int bj = take1 ? j1 : j0;
            int bslot = take1 ? lane + 64 : lane;
            #pragma unroll
            for (int off = 32; off > 0; off >>= 1) {
                float ov = __shfl_down(bv, off);
                int oj = __shfl_down(bj, off);
                int os = __shfl_down(bslot, off);
                if (ov > bv || (ov == bv && oj < bj)) { bv = ov; bj = oj; bslot = os; }
            }
            bslot = __shfl(bslot, 0);
            bv = __shfl(bv, 0);
            bj = __shfl(bj, 0);
            if (lane == 0) { svals[it] = bv; sidxs[it] = bj; }
            if (bslot == lane) v0 = -1.f;
            if (bslot == lane + 64) v1 = -1.f;
        }
    }
    __syncthreads();
    if (t < 32) {
        out_vals[(size_t)n*32 + t] = svals[t];
        out_idx [(size_t)n*32 + t] = sidxs[t];
    }
}

// ---- K5: sparse decode; uint4 gathers (8 bf16/lane, 256B segments/group),
// c-dim split 2x (grid 1024, 4 blocks/CU), padded LDS transpose (conflict-free)
__global__ __launch_bounds__(256) void decode_kernel(const ushort_t* __restrict__ Wdec_bf,
        const float* __restrict__ b_dec, const float* __restrict__ ws_vals,
        const int* __restrict__ ws_idx, float* __restrict__ out) {
    const int bx = blockIdx.x;          // 0..1023
    const int b = bx >> 5, h = (bx >> 1) & 15, cp = bx & 1;
    const int t = threadIdx.x;
    __shared__ float lval[16][33];
    __shared__ int   lidx[16][33];
    __shared__ float s16[16][132];
    __shared__ float s32[16][132];
    {
        int base = (b*256 + h*16) * 32;
        for (int u = t; u < 512; u += 256) {
            lval[u >> 5][u & 31] = ws_vals[base + u];
            lidx[u >> 5][u & 31] = ws_idx[base + u];
        }
    }
    __syncthreads();
    const int w = t >> 4, cl = t & 15;
    const int c_loc = t >> 1, wq = (t & 1) * 8;
    float* o0 = out + FEATS_ELEMS + (size_t)b * XB_STRIDE + h*16;
    float* o1 = o0 + RECON_ELEMS;
    const int cbeg = cp * 640;
    for (int c0 = cbeg; c0 < cbeg + 640; c0 += 128) {
        int c = c0 + 8*cl;
        float a16[8], a32[8];
        #pragma unroll
        for (int q = 0; q < 8; q++) { a16[q] = 0.f; a32[q] = 0.f; }
        #pragma unroll
        for (int j = 0; j < 32; j++) {
            uint4 p = *(const uint4*)&Wdec_bf[(size_t)lidx[w][j] * IN_DIM + c];
            float v = lval[w][j];
            float wv[8];
            wv[0] = __uint_as_float(p.x << 16);
            wv[1] = __uint_as_float(p.x & 0xffff0000u);
            wv[2] = __uint_as_float(p.y << 16);
            wv[3] = __uint_as_float(p.y & 0xffff0000u);
            wv[4] = __uint_as_float(p.z << 16);
            wv[5] = __uint_as_float(p.z & 0xffff0000u);
            wv[6] = __uint_as_float(p.w << 16);
            wv[7] = __uint_as_float(p.w & 0xffff0000u);
            #pragma unroll
            for (int q = 0; q < 8; q++) {
                float pq = v * wv[q];
                if (j < 16) a16[q] += pq;
                a32[q] += pq;
            }
        }
        #pragma unroll
        for (int q = 0; q < 8; q++) {
            float bd = b_dec[c + q];
            s16[w][8*cl + q] = a16[q] + bd;
            s32[w][8*cl + q] = a32[q] + bd;
        }
        __syncthreads();
        f32x4 rA, rB, rC, rD;
        #pragma unroll
        for (int i = 0; i < 4; i++) {
            rA[i] = s16[wq + i][c_loc];
            rB[i] = s16[wq + 4 + i][c_loc];
            rC[i] = s32[wq + i][c_loc];
            rD[i] = s32[wq + 4 + i][c_loc];
        }
        *(f32x4*)&o0[(size_t)(c0 + c_loc)*256 + wq]     = rA;
        *(f32x4*)&o0[(size_t)(c0 + c_loc)*256 + wq + 4] = rB;
        *(f32x4*)&o1[(size_t)(c0 + c_loc)*256 + wq]     = rC;
        *(f32x4*)&o1[(size_t)(c0 + c_loc)*256 + wq + 4] = rD;
        __syncthreads();
    }
}

// ---- K6: fused zero + scatter for the two sparse feats planes ----
__global__ __launch_bounds__(256) void zero_scatter(const float* __restrict__ vals,
        const int* __restrict__ idx, float* __restrict__ feats) {
    const int blk = blockIdx.x;            // 0..16383
    const int copy = blk >> 13;            // 0: k=16 plane, 1: k=32 plane
    const int n = blk & (NROWS - 1);
    float* row = feats + (size_t)copy * NROWS * HID + (size_t)n * HID;
    const int t = threadIdx.x;
    const f32x4 z = {0.f, 0.f, 0.f, 0.f};
    #pragma unroll
    for (int r = 0; r < 5; r++)
        *(f32x4*)&row[(size_t)(t + 256*r) * 4] = z;
    __syncthreads();
    const int k = copy ? 32 : 16;
    if (t < k) {
        row[idx[(size_t)n*32 + t]] = vals[(size_t)n*32 + t];
    }
}

extern "C" void kernel_launch(void* const* d_in, const int* in_sizes, int n_in,
                              void* d_out, int out_size, void* d_ws, size_t ws_size,
                              hipStream_t stream) {
    const float* x     = (const float*)d_in[0];
    const float* W_enc = (const float*)d_in[1];
    const float* b_enc = (const float*)d_in[2];
    const float* W_dec = (const float*)d_in[3];
    const float* b_dec = (const float*)d_in[4];
    float* out = (float*)d_out;

    float* feats0 = out;                                   // [8192][5120]
    float* feats1 = out + (size_t)NROWS * HID;             // [8192][5120]
    float* recon0 = out + FEATS_ELEMS;                     // 10.5M floats
    float* recon1 = recon0 + RECON_ELEMS;                  // 10.5M floats

    // stashes inside not-yet-final output regions:
    ushort_t* Abf = (ushort_t*)recon0;                                   // 21.0 MB
    ushort_t* Wbf = (ushort_t*)recon0 + (size_t)NROWS * IN_DIM;          // 13.1 MB (tot 34.1 < 41.9)
    float*    Wf  = recon1;                                              // 26.2 MB < 41.9
    float*    xT  = feats1;                                              // feats1[0 .. 41.9 MB)
    ushort_t* enc_bf  = (ushort_t*)feats0;                               // 83.9 MB
    ushort_t* Wdec_bf = (ushort_t*)(out + (size_t)22*1024*1024);         // 88 MB into out
    int* cand_idx = (int*)(feats1 + (size_t)16*1024*1024);               // 64MB into feats1
    int* cand_cnt = cand_idx + (size_t)NROWS * CAND_CAP;

    float* ws_vals = (float*)d_ws;                          // 8192*32 floats
    int*   ws_idx  = (int*)d_ws + (size_t)NROWS * 32;       // 8192*32 ints

    convert_all<<<NBLK_A + NBLK_B + NBLK_C, 256, 0, stream>>>(
        x, W_enc, W_dec, Abf, xT, Wbf, Wf, Wdec_bf);
    encode_mfma<<<dim3(HID/BN, NROWS/BM), 256, 0, stream>>>(Abf, Wbf, b_enc, enc_bf);
    topk_approx<<<NROWS, 256, 0, stream>>>(enc_bf, cand_idx, cand_cnt);
    refine_topk<<<NROWS, 256, 0, stream>>>(xT, Wf, b_enc, cand_idx, cand_cnt, ws_vals, ws_idx);
    decode_kernel<<<1024, 256, 0, stream>>>(Wdec_bf, b_dec, ws_vals, ws_idx, out);
    zero_scatter<<<2*NROWS, 256, 0, stream>>>(ws_vals, ws_idx, out);
}

// Round 6
// 894.998 us; speedup vs baseline: 1.1562x; 1.1562x over previous
//
#include <hip/hip_runtime.h>
#include <stdint.h>

#define IN_DIM 1280
#define HID    5120
#define NROWS  8192        // 32*16*16
#define HW     256
#define XB_STRIDE (IN_DIM*HW)             // 327680
#define FEATS_ELEMS (2ull*NROWS*HID)      // 83886080 floats
#define RECON_ELEMS ((size_t)NROWS*IN_DIM) // 10485760 floats

#define CAND_CAP 128
// margin > 2*(gemm bf16 err + bf16 storage half-ulp @ v~1.5) = 2*(0.0075+0.0039)
#define CAND_MARGIN 0.024f

typedef __attribute__((ext_vector_type(8))) short bf16x8;
typedef __attribute__((ext_vector_type(4))) float f32x4;
typedef unsigned short ushort_t;

__device__ inline ushort_t f32_to_bf16(float f) {
    uint32_t u = __float_as_uint(f);
    u += 0x7fff + ((u >> 16) & 1);            // round-to-nearest-even
    return (ushort_t)(u >> 16);
}

__device__ inline float bf16_to_f32(ushort_t h) {
    return __uint_as_float((uint32_t)h << 16);
}

__device__ inline void load_lds16(const void* g, void* l) {
    __builtin_amdgcn_global_load_lds(
        (const __attribute__((address_space(1))) uint32_t*)g,
        (__attribute__((address_space(3))) uint32_t*)l, 16, 0, 0);
}

// ---- K1 (merged): all input conversions in one dispatch ----
#define NBLK_A 10240
#define NBLK_B 6400
#define NBLK_C 6400

__global__ __launch_bounds__(256) void convert_all(const float* __restrict__ x,
        const float* __restrict__ W_enc, const float* __restrict__ W_dec,
        ushort_t* __restrict__ Abf, float* __restrict__ xT,
        ushort_t* __restrict__ Wbf, float* __restrict__ Wf,
        ushort_t* __restrict__ Wdec_bf) {
    __shared__ float s[32][33];
    const int bid = blockIdx.x;
    const int tx = threadIdx.x & 31, ty0 = threadIdx.x >> 5;
    if (bid < NBLK_A) {
        const int c0 = (bid % 40) * 32, hw0 = ((bid / 40) & 7) * 32, b = bid / 320;
        const float* src = x + (size_t)b * XB_STRIDE;
        #pragma unroll
        for (int r = 0; r < 4; r++) {
            int c = c0 + ty0*4 + r;
            s[ty0*4+r][tx] = src[(size_t)c * HW + hw0 + tx];
        }
        __syncthreads();
        #pragma unroll
        for (int r = 0; r < 4; r++) {
            int hw = hw0 + ty0*4 + r;
            int n = b*256 + hw;
            float v = s[tx][ty0*4+r];
            Abf[(size_t)n * IN_DIM + c0 + tx] = f32_to_bf16(v);
            xT [(size_t)n * IN_DIM + c0 + tx] = v;
        }
    } else if (bid < NBLK_A + NBLK_B) {
        const int b2 = bid - NBLK_A;
        const int j0 = (b2 % 160) * 32, c0 = (b2 / 160) * 32;
        #pragma unroll
        for (int r = 0; r < 4; r++) {
            int c = c0 + ty0*4 + r;
            s[ty0*4+r][tx] = W_enc[(size_t)c * HID + j0 + tx];
        }
        __syncthreads();
        #pragma unroll
        for (int r = 0; r < 4; r++) {
            int j = j0 + ty0*4 + r;
            float v = s[tx][ty0*4+r];
            Wbf[(size_t)j * IN_DIM + c0 + tx] = f32_to_bf16(v);
            Wf [(size_t)j * IN_DIM + c0 + tx] = v;
        }
    } else {
        const int b3 = bid - NBLK_A - NBLK_B;
        size_t i = ((size_t)b3 * 256 + threadIdx.x) * 4;
        float4 v = *(const float4*)&W_dec[i];
        Wdec_bf[i+0] = f32_to_bf16(v.x);
        Wdec_bf[i+1] = f32_to_bf16(v.y);
        Wdec_bf[i+2] = f32_to_bf16(v.z);
        Wdec_bf[i+3] = f32_to_bf16(v.w);
    }
}

// ---- K2: bf16 MFMA GEMM, approx enc = relu(A@W + b) -> bf16 store ----
// (round-3 proven version: 128x128 tile, 2560 blocks, ~3 blocks/CU overlap)
#define BM 128
#define BN 128
#define BK 32

__global__ __launch_bounds__(256) void encode_mfma(const ushort_t* __restrict__ A,
        const ushort_t* __restrict__ B, const float* __restrict__ b_enc,
        ushort_t* __restrict__ C) {
    __shared__ __align__(16) ushort_t As[BM*BK];   // [128 rows][32 k] = 8 KB
    __shared__ __align__(16) ushort_t Bs[BN*BK];
    const int n0 = blockIdx.x * BN;
    const int m0 = blockIdx.y * BM;
    const int t = threadIdx.x;
    const int lane = t & 63, w = t >> 6;
    const int mr0 = (w >> 1) * 64, nc0 = (w & 1) * 64;
    const int lm = lane & 15, lq = lane >> 4;
    const int srow_l = w*16 + (lane >> 2);
    const int skof   = (lane & 3) * 8;

    f32x4 acc[4][4];
    #pragma unroll
    for (int i = 0; i < 4; i++)
        #pragma unroll
        for (int j = 0; j < 4; j++)
            #pragma unroll
            for (int q = 0; q < 4; q++) acc[i][j][q] = 0.f;

    for (int k0 = 0; k0 < IN_DIM; k0 += BK) {
        #pragma unroll
        for (int h = 0; h < 2; h++) {
            const ushort_t* ga = &A[(size_t)(m0 + h*64 + srow_l)*IN_DIM + k0 + skof];
            const ushort_t* gb = &B[(size_t)(n0 + h*64 + srow_l)*IN_DIM + k0 + skof];
            load_lds16(ga, &As[(h*64 + w*16)*BK]);
            load_lds16(gb, &Bs[(h*64 + w*16)*BK]);
        }
        __syncthreads();
        bf16x8 af[4], bfr[4];
        #pragma unroll
        for (int mt = 0; mt < 4; mt++)
            af[mt] = *(const bf16x8*)&As[(mr0 + mt*16 + lm)*BK + lq*8];
        #pragma unroll
        for (int nt = 0; nt < 4; nt++)
            bfr[nt] = *(const bf16x8*)&Bs[(nc0 + nt*16 + lm)*BK + lq*8];
        #pragma unroll
        for (int mt = 0; mt < 4; mt++)
            #pragma unroll
            for (int nt = 0; nt < 4; nt++)
                acc[mt][nt] = __builtin_amdgcn_mfma_f32_16x16x32_bf16(af[mt], bfr[nt], acc[mt][nt], 0, 0, 0);
        __syncthreads();
    }
    #pragma unroll
    for (int mt = 0; mt < 4; mt++) {
        #pragma unroll
        for (int nt = 0; nt < 4; nt++) {
            int col = n0 + nc0 + nt*16 + lm;
            float bias = b_enc[col];
            #pragma unroll
            for (int r = 0; r < 4; r++) {
                int row = m0 + mr0 + mt*16 + lq*4 + r;
                float v = acc[mt][nt][r] + bias;
                C[(size_t)row*HID + col] = f32_to_bf16(v > 0.f ? v : 0.f);
            }
        }
    }
}

// ---- K3 (fused): ballot binary-search threshold + LDS compaction + fp32
// exact recompute + ordered exact top-32. One dispatch, no global cand bufs.
__global__ __launch_bounds__(256) void topk_refine(const ushort_t* __restrict__ E,
        const float* __restrict__ xT, const float* __restrict__ Wf,
        const float* __restrict__ b_enc,
        float* __restrict__ out_vals, int* __restrict__ out_idx) {
    const int n = blockIdx.x, t = threadIdx.x;
    const int lane = t & 63, w = t >> 6;
    const int sub = lane >> 4, sl = lane & 15;
    __shared__ __align__(16) float xs[IN_DIM];
    __shared__ int cidx[CAND_CAP];
    __shared__ float cval[CAND_CAP];
    __shared__ float svals[32];
    __shared__ int sidxs[32];
    __shared__ float smx[4];
    __shared__ int scnt[2][4];
    __shared__ int ccount;

    // xs load issued early: overlaps the whole topk phase
    #pragma unroll
    for (int i = 0; i < 5; i++) xs[t + 256*i] = xT[(size_t)n*IN_DIM + t + 256*i];

    // ---- phase 1: approx-rank-32 threshold on bf16 enc row ----
    const ushort_t* row = E + (size_t)n * HID;
    float v[20];
    {
        bf16x8 u0 = *(const bf16x8*)&row[t*16];
        bf16x8 u1 = *(const bf16x8*)&row[t*16 + 8];
        #pragma unroll
        for (int r = 0; r < 8; r++) {
            v[r]   = bf16_to_f32((ushort_t)u0[r]);
            v[r+8] = bf16_to_f32((ushort_t)u1[r]);
        }
        ushort_t u2[4];
        *(uint2*)u2 = *(const uint2*)&row[4096 + t*4];
        #pragma unroll
        for (int r = 0; r < 4; r++) v[16+r] = bf16_to_f32(u2[r]);
    }
    float mx = 0.f;
    #pragma unroll
    for (int r = 0; r < 20; r++) mx = fmaxf(mx, v[r]);
    #pragma unroll
    for (int off = 32; off > 0; off >>= 1) mx = fmaxf(mx, __shfl_down(mx, off));
    if ((t & 63) == 0) smx[t >> 6] = mx;
    if (t == 0) ccount = 0;
    __syncthreads();
    float lo = 0.f;
    float hi = fmaxf(fmaxf(smx[0], smx[1]), fmaxf(smx[2], smx[3])) + 1e-6f;
    for (int it = 0; it < 11; it++) {
        float mid = 0.5f * (lo + hi);
        int c = 0;
        #pragma unroll
        for (int r = 0; r < 20; r++)
            c += (int)__popcll(__ballot(v[r] > mid));
        if ((t & 63) == 0) scnt[it & 1][t >> 6] = c;
        __syncthreads();
        int tot = scnt[it & 1][0] + scnt[it & 1][1] + scnt[it & 1][2] + scnt[it & 1][3];
        if (tot >= 32) lo = mid; else hi = mid;
    }
    float thr = lo - CAND_MARGIN;
    #pragma unroll
    for (int r = 0; r < 20; r++) {
        if (v[r] > thr) {
            int p = atomicAdd(&ccount, 1);
            int idx = (r < 16) ? (16*t + r) : (4096 + 4*t + (r - 16));
            if (p < CAND_CAP) cidx[p] = idx;
        }
    }
    __syncthreads();
    const int cnt = ccount < CAND_CAP ? ccount : CAND_CAP;
    if (t < CAND_CAP) {
        cval[t] = -1.f;
        if (t >= cnt) cidx[t] = 0x7fffffff;
    }
    __syncthreads();

    // ---- phase 2: fp32 exact recompute of candidates ----
    const int slot = w*4 + sub;          // 0..15
    const int iters = (cnt + 15) >> 4;
    for (int it = 0; it < iters; it++) {
        int i = it*16 + slot;
        if (i < cnt) {
            int j = cidx[i];
            const float4* wr2 = (const float4*)(Wf + (size_t)j * IN_DIM);
            const float4* xr = (const float4*)xs;
            float a0 = 0.f, a1 = 0.f, a2 = 0.f, a3 = 0.f;
            #pragma unroll
            for (int r = 0; r < 20; r++) {
                float4 wv = wr2[sl + 16*r];
                float4 xv = xr[sl + 16*r];
                a0 = fmaf(xv.x, wv.x, a0);
                a1 = fmaf(xv.y, wv.y, a1);
                a2 = fmaf(xv.z, wv.z, a2);
                a3 = fmaf(xv.w, wv.w, a3);
            }
            float s = (a0 + a1) + (a2 + a3);
            #pragma unroll
            for (int off = 8; off > 0; off >>= 1)
                s += __shfl_down(s, off);
            if (sl == 0) {
                float fv = s + b_enc[j];
                cval[i] = fv > 0.f ? fv : 0.f;
            }
        }
    }
    __syncthreads();

    // ---- phase 3: ordered exact top-32 (wave 0) ----
    if (w == 0) {
        float v0 = cval[lane], v1 = cval[lane + 64];
        int j0 = cidx[lane], j1 = cidx[lane + 64];
        for (int it = 0; it < 32; it++) {
            bool take1 = (v1 > v0) || (v1 == v0 && j1 < j0);
            float bv = take1 ? v1 : v0;
            int bj = take1 ? j1 : j0;
            int bslot = take1 ? lane + 64 : lane;
            #pragma unroll
            for (int off = 32; off > 0; off >>= 1) {
                float ov = __shfl_down(bv, off);
                int oj = __shfl_down(bj, off);
                int os = __shfl_down(bslot, off);
                if (ov > bv || (ov == bv && oj < bj)) { bv = ov; bj = oj; bslot = os; }
            }
            bslot = __shfl(bslot, 0);
            bv = __shfl(bv, 0);
            bj = __shfl(bj, 0);
            if (lane == 0) { svals[it] = bv; sidxs[it] = bj; }
            if (bslot == lane) v0 = -1.f;
            if (bslot == lane + 64) v1 = -1.f;
        }
    }
    __syncthreads();
    if (t < 32) {
        out_vals[(size_t)n*32 + t] = svals[t];
        out_idx [(size_t)n*32 + t] = sidxs[t];
    }
}

// ---- K5: sparse decode (round-3 proven version); uint2 gathers, LDS-staged
// full-line stores ----
__global__ __launch_bounds__(256) void decode_kernel(const ushort_t* __restrict__ Wdec_bf,
        const float* __restrict__ b_dec, const float* __restrict__ ws_vals,
        const int* __restrict__ ws_idx, float* __restrict__ out) {
    const int bx = blockIdx.x;          // 0..511
    const int b = bx >> 4, h = bx & 15;
    const int t = threadIdx.x;
    __shared__ float lval[16][33];
    __shared__ int   lidx[16][33];
    __shared__ float s16[16][64];
    __shared__ float s32[16][64];
    {
        int base = (b*256 + h*16) * 32;
        for (int u = t; u < 512; u += 256) {
            lval[u >> 5][u & 31] = ws_vals[base + u];
            lidx[u >> 5][u & 31] = ws_idx[base + u];
        }
    }
    __syncthreads();
    const int w = t >> 4, cl = t & 15;
    const int c_loc = t >> 2, wq = (t & 3) * 4;
    float* o0 = out + FEATS_ELEMS + (size_t)b * XB_STRIDE + h*16;
    float* o1 = o0 + RECON_ELEMS;
    for (int c0 = 0; c0 < IN_DIM; c0 += 64) {
        int c = c0 + 4*cl;
        float a16[4] = {0.f,0.f,0.f,0.f}, a32[4] = {0.f,0.f,0.f,0.f};
        #pragma unroll
        for (int j = 0; j < 32; j++) {
            uint2 p = *(const uint2*)&Wdec_bf[(size_t)lidx[w][j] * IN_DIM + c];
            float w0 = __uint_as_float(p.x << 16);
            float w1 = __uint_as_float(p.x & 0xffff0000u);
            float w2 = __uint_as_float(p.y << 16);
            float w3 = __uint_as_float(p.y & 0xffff0000u);
            float v = lval[w][j];
            float p0 = v*w0, p1 = v*w1, p2 = v*w2, p3 = v*w3;
            if (j < 16) { a16[0]+=p0; a16[1]+=p1; a16[2]+=p2; a16[3]+=p3; }
            a32[0]+=p0; a32[1]+=p1; a32[2]+=p2; a32[3]+=p3;
        }
        f32x4 t16, t32;
        #pragma unroll
        for (int q = 0; q < 4; q++) {
            float bd = b_dec[c+q];
            t16[q] = a16[q] + bd;
            t32[q] = a32[q] + bd;
        }
        *(f32x4*)&s16[w][4*cl] = t16;
        *(f32x4*)&s32[w][4*cl] = t32;
        __syncthreads();
        f32x4 r16, r32;
        #pragma unroll
        for (int i = 0; i < 4; i++) {
            r16[i] = s16[wq + i][c_loc];
            r32[i] = s32[wq + i][c_loc];
        }
        *(f32x4*)&o0[(size_t)(c0 + c_loc)*256 + wq] = r16;
        *(f32x4*)&o1[(size_t)(c0 + c_loc)*256 + wq] = r32;
        __syncthreads();
    }
}

// ---- K6: fused zero + scatter for the two sparse feats planes ----
__global__ __launch_bounds__(256) void zero_scatter(const float* __restrict__ vals,
        const int* __restrict__ idx, float* __restrict__ feats) {
    const int blk = blockIdx.x;            // 0..16383
    const int copy = blk >> 13;            // 0: k=16 plane, 1: k=32 plane
    const int n = blk & (NROWS - 1);
    float* row = feats + (size_t)copy * NROWS * HID + (size_t)n * HID;
    const int t = threadIdx.x;
    const f32x4 z = {0.f, 0.f, 0.f, 0.f};
    #pragma unroll
    for (int r = 0; r < 5; r++)
        *(f32x4*)&row[(size_t)(t + 256*r) * 4] = z;
    __syncthreads();
    const int k = copy ? 32 : 16;
    if (t < k) {
        row[idx[(size_t)n*32 + t]] = vals[(size_t)n*32 + t];
    }
}

extern "C" void kernel_launch(void* const* d_in, const int* in_sizes, int n_in,
                              void* d_out, int out_size, void* d_ws, size_t ws_size,
                              hipStream_t stream) {
    const float* x     = (const float*)d_in[0];
    const float* W_enc = (const float*)d_in[1];
    const float* b_enc = (const float*)d_in[2];
    const float* W_dec = (const float*)d_in[3];
    const float* b_dec = (const float*)d_in[4];
    float* out = (float*)d_out;

    float* feats0 = out;                                   // [8192][5120]
    float* feats1 = out + (size_t)NROWS * HID;             // [8192][5120]
    float* recon0 = out + FEATS_ELEMS;                     // 10.5M floats
    float* recon1 = recon0 + RECON_ELEMS;                  // 10.5M floats

    // stashes inside not-yet-final output regions:
    ushort_t* Abf = (ushort_t*)recon0;                                   // 21.0 MB
    ushort_t* Wbf = (ushort_t*)recon0 + (size_t)NROWS * IN_DIM;          // 13.1 MB (tot 34.1 < 41.9)
    float*    Wf  = recon1;                                              // 26.2 MB < 41.9
    float*    xT  = feats1;                                              // feats1[0 .. 41.9 MB)
    ushort_t* enc_bf  = (ushort_t*)feats0;                               // 83.9 MB
    ushort_t* Wdec_bf = (ushort_t*)(out + (size_t)22*1024*1024);         // 88 MB into out
    float* ws_vals = (float*)d_ws;                          // 8192*32 floats
    int*   ws_idx  = (int*)d_ws + (size_t)NROWS * 32;       // 8192*32 ints

    convert_all<<<NBLK_A + NBLK_B + NBLK_C, 256, 0, stream>>>(
        x, W_enc, W_dec, Abf, xT, Wbf, Wf, Wdec_bf);
    encode_mfma<<<dim3(HID/BN, NROWS/BM), 256, 0, stream>>>(Abf, Wbf, b_enc, enc_bf);
    topk_refine<<<NROWS, 256, 0, stream>>>(enc_bf, xT, Wf, b_enc, ws_vals, ws_idx);
    decode_kernel<<<512, 256, 0, stream>>>(Wdec_bf, b_dec, ws_vals, ws_idx, out);
    zero_scatter<<<2*NROWS, 256, 0, stream>>>(ws_vals, ws_idx, out);
}

// Round 8
// 870.107 us; speedup vs baseline: 1.1893x; 1.0286x over previous
//
#include <hip/hip_runtime.h>
#include <stdint.h>

#define IN_DIM 1280
#define HID    5120
#define NROWS  8192        // 32*16*16
#define HW     256
#define XB_STRIDE (IN_DIM*HW)             // 327680
#define FEATS_ELEMS (2ull*NROWS*HID)      // 83886080 floats
#define RECON_ELEMS ((size_t)NROWS*IN_DIM) // 10485760 floats

#define CAND_CAP 128
// margin > 2*(gemm bf16 err + bf16 storage half-ulp @ v~1.5) = 2*(0.0075+0.0039)
#define CAND_MARGIN 0.024f

typedef __attribute__((ext_vector_type(8))) short bf16x8;
typedef __attribute__((ext_vector_type(4))) float f32x4;
typedef unsigned short ushort_t;

__device__ inline ushort_t f32_to_bf16(float f) {
    uint32_t u = __float_as_uint(f);
    u += 0x7fff + ((u >> 16) & 1);            // round-to-nearest-even
    return (ushort_t)(u >> 16);
}

__device__ inline float bf16_to_f32(ushort_t h) {
    return __uint_as_float((uint32_t)h << 16);
}

__device__ inline void load_lds16(const void* g, void* l) {
    __builtin_amdgcn_global_load_lds(
        (const __attribute__((address_space(1))) uint32_t*)g,
        (__attribute__((address_space(3))) uint32_t*)l, 16, 0, 0);
}

// ---- K1 (merged): all input conversions in one dispatch ----
#define NBLK_A 10240
#define NBLK_B 6400
#define NBLK_C 6400

__global__ __launch_bounds__(256) void convert_all(const float* __restrict__ x,
        const float* __restrict__ W_enc, const float* __restrict__ W_dec,
        ushort_t* __restrict__ Abf, float* __restrict__ xT,
        ushort_t* __restrict__ Wbf, float* __restrict__ Wf,
        ushort_t* __restrict__ Wdec_bf) {
    __shared__ float s[32][33];
    const int bid = blockIdx.x;
    const int tx = threadIdx.x & 31, ty0 = threadIdx.x >> 5;
    if (bid < NBLK_A) {
        const int c0 = (bid % 40) * 32, hw0 = ((bid / 40) & 7) * 32, b = bid / 320;
        const float* src = x + (size_t)b * XB_STRIDE;
        #pragma unroll
        for (int r = 0; r < 4; r++) {
            int c = c0 + ty0*4 + r;
            s[ty0*4+r][tx] = src[(size_t)c * HW + hw0 + tx];
        }
        __syncthreads();
        #pragma unroll
        for (int r = 0; r < 4; r++) {
            int hw = hw0 + ty0*4 + r;
            int n = b*256 + hw;
            float v = s[tx][ty0*4+r];
            Abf[(size_t)n * IN_DIM + c0 + tx] = f32_to_bf16(v);
            xT [(size_t)n * IN_DIM + c0 + tx] = v;
        }
    } else if (bid < NBLK_A + NBLK_B) {
        const int b2 = bid - NBLK_A;
        const int j0 = (b2 % 160) * 32, c0 = (b2 / 160) * 32;
        #pragma unroll
        for (int r = 0; r < 4; r++) {
            int c = c0 + ty0*4 + r;
            s[ty0*4+r][tx] = W_enc[(size_t)c * HID + j0 + tx];
        }
        __syncthreads();
        #pragma unroll
        for (int r = 0; r < 4; r++) {
            int j = j0 + ty0*4 + r;
            float v = s[tx][ty0*4+r];
            Wbf[(size_t)j * IN_DIM + c0 + tx] = f32_to_bf16(v);
            Wf [(size_t)j * IN_DIM + c0 + tx] = v;
        }
    } else {
        const int b3 = bid - NBLK_A - NBLK_B;
        size_t i = ((size_t)b3 * 256 + threadIdx.x) * 4;
        float4 v = *(const float4*)&W_dec[i];
        Wdec_bf[i+0] = f32_to_bf16(v.x);
        Wdec_bf[i+1] = f32_to_bf16(v.y);
        Wdec_bf[i+2] = f32_to_bf16(v.z);
        Wdec_bf[i+3] = f32_to_bf16(v.w);
    }
}

// ---- K2: bf16 MFMA GEMM (128x128 tile, BK=64, XOR-swizzled LDS) ----
#define BM 128
#define BN 128
#define BK 64

__global__ __launch_bounds__(256) void encode_mfma(const ushort_t* __restrict__ A,
        const ushort_t* __restrict__ B, const float* __restrict__ b_enc,
        ushort_t* __restrict__ C) {
    __shared__ __align__(16) ushort_t As[BM*BK];   // 16 KB
    __shared__ __align__(16) ushort_t Bs[BN*BK];   // 16 KB
    const int n0 = blockIdx.x * BN;
    const int m0 = blockIdx.y * BM;
    const int t = threadIdx.x;
    const int lane = t & 63, w = t >> 6;
    const int mr0 = (w >> 1) * 64, nc0 = (w & 1) * 64;
    const int lm = lane & 15, lq = lane >> 4;

    f32x4 acc[4][4];
    #pragma unroll
    for (int i = 0; i < 4; i++)
        #pragma unroll
        for (int j = 0; j < 4; j++)
            #pragma unroll
            for (int q = 0; q < 4; q++) acc[i][j][q] = 0.f;

    #define STAGE32(OPA, kt, rbase) do {                                         \
        int row_ = (rbase) + w*8 + (lane >> 3);                                  \
        int ch_ = (lane & 7) ^ (row_ & 7);                                       \
        const ushort_t* g_ = ((OPA) ? &A[(size_t)(m0+row_)*IN_DIM]               \
                                    : &B[(size_t)(n0+row_)*IN_DIM])              \
                             + (kt) + ch_*8;                                     \
        ushort_t* l_ = ((OPA) ? As : Bs) + ((rbase) + w*8)*BK;                   \
        load_lds16(g_, l_);                                                      \
    } while (0)
    #define RDA(dst, mt, kk) do {                                                \
        int r_ = mr0 + (mt)*16 + lm;                                             \
        int ch_ = ((kk)*4 + lq) ^ (r_ & 7);                                      \
        dst = *(const bf16x8*)&As[r_*BK + ch_*8];                                \
    } while (0)
    #define RDB(dst, nt, kk) do {                                                \
        int r_ = nc0 + (nt)*16 + lm;                                             \
        int ch_ = ((kk)*4 + lq) ^ (r_ & 7);                                      \
        dst = *(const bf16x8*)&Bs[r_*BK + ch_*8];                                \
    } while (0)

    for (int k0 = 0; k0 < IN_DIM; k0 += BK) {
        STAGE32(1, k0, 0); STAGE32(1, k0, 32); STAGE32(1, k0, 64); STAGE32(1, k0, 96);
        STAGE32(0, k0, 0); STAGE32(0, k0, 32); STAGE32(0, k0, 64); STAGE32(0, k0, 96);
        __syncthreads();
        bf16x8 af[2][4], bfr[2][4];
        #pragma unroll
        for (int kk = 0; kk < 2; kk++) {
            #pragma unroll
            for (int mt = 0; mt < 4; mt++) RDA(af[kk][mt], mt, kk);
            #pragma unroll
            for (int nt = 0; nt < 4; nt++) RDB(bfr[kk][nt], nt, kk);
        }
        #pragma unroll
        for (int kk = 0; kk < 2; kk++)
            #pragma unroll
            for (int mt = 0; mt < 4; mt++)
                #pragma unroll
                for (int nt = 0; nt < 4; nt++)
                    acc[mt][nt] = __builtin_amdgcn_mfma_f32_16x16x32_bf16(
                        af[kk][mt], bfr[kk][nt], acc[mt][nt], 0, 0, 0);
        __syncthreads();
    }
    #undef STAGE32
    #undef RDA
    #undef RDB
    #pragma unroll
    for (int mt = 0; mt < 4; mt++) {
        #pragma unroll
        for (int nt = 0; nt < 4; nt++) {
            int col = n0 + nc0 + nt*16 + lm;
            float bias = b_enc[col];
            #pragma unroll
            for (int r = 0; r < 4; r++) {
                int row = m0 + mr0 + mt*16 + lq*4 + r;
                float v = acc[mt][nt][r] + bias;
                C[(size_t)row*HID + col] = f32_to_bf16(v > 0.f ? v : 0.f);
            }
        }
    }
}

// ---- K3 (fused): ballot binary-search threshold + LDS compaction + fp32
// exact recompute + ordered exact top-32. One dispatch, no global cand bufs.
__global__ __launch_bounds__(256) void topk_refine(const ushort_t* __restrict__ E,
        const float* __restrict__ xT, const float* __restrict__ Wf,
        const float* __restrict__ b_enc,
        float* __restrict__ out_vals, int* __restrict__ out_idx) {
    const int n = blockIdx.x, t = threadIdx.x;
    const int lane = t & 63, w = t >> 6;
    const int sub = lane >> 4, sl = lane & 15;
    __shared__ __align__(16) float xs[IN_DIM];
    __shared__ int cidx[CAND_CAP];
    __shared__ float cval[CAND_CAP];
    __shared__ float svals[32];
    __shared__ int sidxs[32];
    __shared__ float smx[4];
    __shared__ int scnt[2][4];
    __shared__ int ccount;

    #pragma unroll
    for (int i = 0; i < 5; i++) xs[t + 256*i] = xT[(size_t)n*IN_DIM + t + 256*i];

    const ushort_t* row = E + (size_t)n * HID;
    float v[20];
    {
        bf16x8 u0 = *(const bf16x8*)&row[t*16];
        bf16x8 u1 = *(const bf16x8*)&row[t*16 + 8];
        #pragma unroll
        for (int r = 0; r < 8; r++) {
            v[r]   = bf16_to_f32((ushort_t)u0[r]);
            v[r+8] = bf16_to_f32((ushort_t)u1[r]);
        }
        ushort_t u2[4];
        *(uint2*)u2 = *(const uint2*)&row[4096 + t*4];
        #pragma unroll
        for (int r = 0; r < 4; r++) v[16+r] = bf16_to_f32(u2[r]);
    }
    float mx = 0.f;
    #pragma unroll
    for (int r = 0; r < 20; r++) mx = fmaxf(mx, v[r]);
    #pragma unroll
    for (int off = 32; off > 0; off >>= 1) mx = fmaxf(mx, __shfl_down(mx, off));
    if ((t & 63) == 0) smx[t >> 6] = mx;
    if (t == 0) ccount = 0;
    __syncthreads();
    float lo = 0.f;
    float hi = fmaxf(fmaxf(smx[0], smx[1]), fmaxf(smx[2], smx[3])) + 1e-6f;
    for (int it = 0; it < 11; it++) {
        float mid = 0.5f * (lo + hi);
        int c = 0;
        #pragma unroll
        for (int r = 0; r < 20; r++)
            c += (int)__popcll(__ballot(v[r] > mid));
        if ((t & 63) == 0) scnt[it & 1][t >> 6] = c;
        __syncthreads();
        int tot = scnt[it & 1][0] + scnt[it & 1][1] + scnt[it & 1][2] + scnt[it & 1][3];
        if (tot >= 32) lo = mid; else hi = mid;
    }
    float thr = lo - CAND_MARGIN;
    #pragma unroll
    for (int r = 0; r < 20; r++) {
        if (v[r] > thr) {
            int p = atomicAdd(&ccount, 1);
            int idx = (r < 16) ? (16*t + r) : (4096 + 4*t + (r - 16));
            if (p < CAND_CAP) cidx[p] = idx;
        }
    }
    __syncthreads();
    const int cnt = ccount < CAND_CAP ? ccount : CAND_CAP;
    if (t < CAND_CAP) {
        cval[t] = -1.f;
        if (t >= cnt) cidx[t] = 0x7fffffff;
    }
    __syncthreads();

    const int slot = w*4 + sub;          // 0..15
    const int iters = (cnt + 15) >> 4;
    for (int it = 0; it < iters; it++) {
        int i = it*16 + slot;
        if (i < cnt) {
            int j = cidx[i];
            const float4* wr2 = (const float4*)(Wf + (size_t)j * IN_DIM);
            const float4* xr = (const float4*)xs;
            float a0 = 0.f, a1 = 0.f, a2 = 0.f, a3 = 0.f;
            #pragma unroll
            for (int r = 0; r < 20; r++) {
                float4 wv = wr2[sl + 16*r];
                float4 xv = xr[sl + 16*r];
                a0 = fmaf(xv.x, wv.x, a0);
                a1 = fmaf(xv.y, wv.y, a1);
                a2 = fmaf(xv.z, wv.z, a2);
                a3 = fmaf(xv.w, wv.w, a3);
            }
            float s = (a0 + a1) + (a2 + a3);
            #pragma unroll
            for (int off = 8; off > 0; off >>= 1)
                s += __shfl_down(s, off);
            if (sl == 0) {
                float fv = s + b_enc[j];
                cval[i] = fv > 0.f ? fv : 0.f;
            }
        }
    }
    __syncthreads();

    if (w == 0) {
        float v0 = cval[lane], v1 = cval[lane + 64];
        int j0 = cidx[lane], j1 = cidx[lane + 64];
        for (int it = 0; it < 32; it++) {
            bool take1 = (v1 > v0) || (v1 == v0 && j1 < j0);
            float bv = take1 ? v1 : v0;
            int bj = take1 ? j1 : j0;
            int bslot = take1 ? lane + 64 : lane;
            #pragma unroll
            for (int off = 32; off > 0; off >>= 1) {
                float ov = __shfl_down(bv, off);
                int oj = __shfl_down(bj, off);
                int os = __shfl_down(bslot, off);
                if (ov > bv || (ov == bv && oj < bj)) { bv = ov; bj = oj; bslot = os; }
            }
            bslot = __shfl(bslot, 0);
            bv = __shfl(bv, 0);
            bj = __shfl(bj, 0);
            if (lane == 0) { svals[it] = bv; sidxs[it] = bj; }
            if (bslot == lane) v0 = -1.f;
            if (bslot == lane + 64) v1 = -1.f;
        }
    }
    __syncthreads();
    if (t < 32) {
        out_vals[(size_t)n*32 + t] = svals[t];
        out_idx [(size_t)n*32 + t] = sidxs[t];
    }
}

// ---- K5: sparse decode; uint2 gathers, LDS-staged full-line stores,
// c-split 2x for occupancy (grid 1024, 4 blocks/CU) ----
__global__ __launch_bounds__(256) void decode_kernel(const ushort_t* __restrict__ Wdec_bf,
        const float* __restrict__ b_dec, const float* __restrict__ ws_vals,
        const int* __restrict__ ws_idx, float* __restrict__ out) {
    const int bx = blockIdx.x;          // 0..1023
    const int b = bx >> 5, h = (bx >> 1) & 15, cp = bx & 1;
    const int t = threadIdx.x;
    __shared__ float lval[16][33];
    __shared__ int   lidx[16][33];
    __shared__ float s16[16][64];
    __shared__ float s32[16][64];
    {
        int base = (b*256 + h*16) * 32;
        for (int u = t; u < 512; u += 256) {
            lval[u >> 5][u & 31] = ws_vals[base + u];
            lidx[u >> 5][u & 31] = ws_idx[base + u];
        }
    }
    __syncthreads();
    const int w = t >> 4, cl = t & 15;
    const int c_loc = t >> 2, wq = (t & 3) * 4;
    float* o0 = out + FEATS_ELEMS + (size_t)b * XB_STRIDE + h*16;
    float* o1 = o0 + RECON_ELEMS;
    const int cbeg = cp * 640;
    for (int c0 = cbeg; c0 < cbeg + 640; c0 += 64) {
        int c = c0 + 4*cl;
        float a16[4] = {0.f,0.f,0.f,0.f}, a32[4] = {0.f,0.f,0.f,0.f};
        #pragma unroll
        for (int j = 0; j < 32; j++) {
            uint2 p = *(const uint2*)&Wdec_bf[(size_t)lidx[w][j] * IN_DIM + c];
            float w0 = __uint_as_float(p.x << 16);
            float w1 = __uint_as_float(p.x & 0xffff0000u);
            float w2 = __uint_as_float(p.y << 16);
            float w3 = __uint_as_float(p.y & 0xffff0000u);
            float v = lval[w][j];
            float p0 = v*w0, p1 = v*w1, p2 = v*w2, p3 = v*w3;
            if (j < 16) { a16[0]+=p0; a16[1]+=p1; a16[2]+=p2; a16[3]+=p3; }
            a32[0]+=p0; a32[1]+=p1; a32[2]+=p2; a32[3]+=p3;
        }
        f32x4 t16, t32;
        #pragma unroll
        for (int q = 0; q < 4; q++) {
            float bd = b_dec[c+q];
            t16[q] = a16[q] + bd;
            t32[q] = a32[q] + bd;
        }
        *(f32x4*)&s16[w][4*cl] = t16;
        *(f32x4*)&s32[w][4*cl] = t32;
        __syncthreads();
        f32x4 r16, r32;
        #pragma unroll
        for (int i = 0; i < 4; i++) {
            r16[i] = s16[wq + i][c_loc];   // FIXED: was [c_loc & 15]
            r32[i] = s32[wq + i][c_loc];
        }
        *(f32x4*)&o0[(size_t)(c0 + c_loc)*256 + wq] = r16;
        *(f32x4*)&o1[(size_t)(c0 + c_loc)*256 + wq] = r32;
        __syncthreads();
    }
}

// ---- K6: fused zero + scatter for the two sparse feats planes ----
__global__ __launch_bounds__(256) void zero_scatter(const float* __restrict__ vals,
        const int* __restrict__ idx, float* __restrict__ feats) {
    const int blk = blockIdx.x;            // 0..16383
    const int copy = blk >> 13;            // 0: k=16 plane, 1: k=32 plane
    const int n = blk & (NROWS - 1);
    float* row = feats + (size_t)copy * NROWS * HID + (size_t)n * HID;
    const int t = threadIdx.x;
    const f32x4 z = {0.f, 0.f, 0.f, 0.f};
    #pragma unroll
    for (int r = 0; r < 5; r++)
        *(f32x4*)&row[(size_t)(t + 256*r) * 4] = z;
    __syncthreads();
    const int k = copy ? 32 : 16;
    if (t < k) {
        row[idx[(size_t)n*32 + t]] = vals[(size_t)n*32 + t];
    }
}

extern "C" void kernel_launch(void* const* d_in, const int* in_sizes, int n_in,
                              void* d_out, int out_size, void* d_ws, size_t ws_size,
                              hipStream_t stream) {
    const float* x     = (const float*)d_in[0];
    const float* W_enc = (const float*)d_in[1];
    const float* b_enc = (const float*)d_in[2];
    const float* W_dec = (const float*)d_in[3];
    const float* b_dec = (const float*)d_in[4];
    float* out = (float*)d_out;

    float* feats0 = out;                                   // [8192][5120]
    float* feats1 = out + (size_t)NROWS * HID;             // [8192][5120]
    float* recon0 = out + FEATS_ELEMS;                     // 10.5M floats
    float* recon1 = recon0 + RECON_ELEMS;                  // 10.5M floats

    // stashes inside not-yet-final output regions:
    ushort_t* Abf = (ushort_t*)recon0;                                   // 21.0 MB
    ushort_t* Wbf = (ushort_t*)recon0 + (size_t)NROWS * IN_DIM;          // 13.1 MB (tot 34.1 < 41.9)
    float*    Wf  = recon1;                                              // 26.2 MB < 41.9
    float*    xT  = feats1;                                              // feats1[0 .. 41.9 MB)
    ushort_t* enc_bf  = (ushort_t*)feats0;                               // 83.9 MB
    ushort_t* Wdec_bf = (ushort_t*)(out + (size_t)22*1024*1024);         // 88 MB into out
    float* ws_vals = (float*)d_ws;                          // 8192*32 floats
    int*   ws_idx  = (int*)d_ws + (size_t)NROWS * 32;       // 8192*32 ints

    convert_all<<<NBLK_A + NBLK_B + NBLK_C, 256, 0, stream>>>(
        x, W_enc, W_dec, Abf, xT, Wbf, Wf, Wdec_bf);
    encode_mfma<<<dim3(HID/BN, NROWS/BM), 256, 0, stream>>>(Abf, Wbf, b_enc, enc_bf);
    topk_refine<<<NROWS, 256, 0, stream>>>(enc_bf, xT, Wf, b_enc, ws_vals, ws_idx);
    decode_kernel<<<1024, 256, 0, stream>>>(Wdec_bf, b_dec, ws_vals, ws_idx, out);
    zero_scatter<<<2*NROWS, 256, 0, stream>>>(ws_vals, ws_idx, out);
}